// Round 1
// baseline (925.196 us; speedup 1.0000x reference)
//
#include <hip/hip_runtime.h>
#include <hip/hip_bf16.h>
#include <cstdint>
#include <cstdio>

// DroplessMoE on MI355X.
// Sizes (fixed by setup_inputs): B=4,S=1024 -> T=4096 tokens, H=1024, F=4096, E=8, top-2.
// d_in: x[T,H] f32, gate_w[E,H] f32, w1[E,H,F] f32, b1[E,F] f32, w2[E,F,H] f32, b2[E,H] f32
// d_out: final[T,H] f32, then z_loss, aux_loss (out_size = T*H + 2)

typedef uint16_t u16;
typedef __attribute__((ext_vector_type(8))) short short8;
typedef __attribute__((ext_vector_type(4))) float f32x4;

#define T_TOK 4096
#define HDIM  1024
#define FDIM  4096
#define NEXP  8
#define NASSIGN (T_TOK * 2)   // total (token,slot) assignments = 8192 exactly

// ---------- ws layout (bytes) ----------
static constexpr size_t WS_SCAL = 0;                         // 8 floats
static constexpr size_t WS_CNT  = 64;                        // 8 ints
static constexpr size_t WS_LIST = 256;                       // 8 * 8192 ints
static constexpr size_t WS_AW   = WS_LIST + (size_t)NEXP * NASSIGN * 4;   // 8192 floats
static constexpr size_t WS_XBF  = WS_AW + (size_t)NASSIGN * 4;            // T*H bf16
static constexpr size_t WS_W1T  = WS_XBF + (size_t)T_TOK * HDIM * 2;      // E*F*H bf16 (transposed)
static constexpr size_t WS_W2T  = WS_W1T + (size_t)NEXP * FDIM * HDIM * 2;// E*H*F bf16 (transposed)
static constexpr size_t WS_H1   = WS_W2T + (size_t)NEXP * FDIM * HDIM * 2;// NASSIGN*F bf16
static constexpr size_t WS_END  = WS_H1 + (size_t)NASSIGN * FDIM * 2;     // ~210 MB

__device__ __forceinline__ u16 f2bf(float v) {
  union { float f; uint32_t u; } c; c.f = v;
  uint32_t r = c.u + 0x7fffu + ((c.u >> 16) & 1u);
  return (u16)(r >> 16);
}

__device__ __forceinline__ void gload16(const void* g, void* l) {
  __builtin_amdgcn_global_load_lds(
      (const __attribute__((address_space(1))) void*)g,
      (__attribute__((address_space(3))) void*)l, 16, 0, 0);
}

// ---------- x fp32 -> bf16 ----------
__global__ __launch_bounds__(256) void cvt_x_kernel(const float* __restrict__ x,
                                                    u16* __restrict__ xb) {
  int i = blockIdx.x * 256 + threadIdx.x;       // grid covers T*H/4
  float4 v = ((const float4*)x)[i];
  ushort4 o;
  o.x = f2bf(v.x); o.y = f2bf(v.y); o.z = f2bf(v.z); o.w = f2bf(v.w);
  ((ushort4*)xb)[i] = o;
}

// ---------- tiled transpose + fp32->bf16:  src [E][R][C] f32 -> dst [E][C][R] bf16 ----------
__global__ __launch_bounds__(256) void transpose_cvt(const float* __restrict__ src,
                                                     u16* __restrict__ dst,
                                                     int R, int C) {
  int e = blockIdx.z;
  const float* s = src + (size_t)e * R * C;
  u16* d = dst + (size_t)e * R * C;
  int r0 = blockIdx.y * 64, c0 = blockIdx.x * 64;
  __shared__ u16 tile[64][66];
  int tid = threadIdx.x;
  int col = tid & 63, rr = tid >> 6;
#pragma unroll
  for (int i = 0; i < 16; ++i) {
    int r = i * 4 + rr;
    tile[r][col] = f2bf(s[(size_t)(r0 + r) * C + c0 + col]);
  }
  __syncthreads();
  int p = tid & 31, orr = tid >> 5;
#pragma unroll
  for (int i = 0; i < 8; ++i) {
    int orow = i * 8 + orr;                         // out row within tile (C dim)
    uint32_t pk = (uint32_t)tile[2 * p][orow] | ((uint32_t)tile[2 * p + 1][orow] << 16);
    *(uint32_t*)&d[(size_t)(c0 + orow) * R + r0 + 2 * p] = pk;
  }
}

// ---------- router: logits, softmax, top-2, losses, scatter ----------
__global__ __launch_bounds__(256) void router_kernel(const float* __restrict__ x,
                                                     const float* __restrict__ gw,
                                                     float* __restrict__ scal,
                                                     int* __restrict__ counts,
                                                     int* __restrict__ lists,
                                                     float* __restrict__ aw) {
  int wv = threadIdx.x >> 6, lane = threadIdx.x & 63;
  int t = blockIdx.x * 4 + wv;
  const float* xr = x + (size_t)t * HDIM;
  float acc[NEXP] = {0.f, 0.f, 0.f, 0.f, 0.f, 0.f, 0.f, 0.f};
#pragma unroll
  for (int i = 0; i < 16; ++i) {
    float xv = xr[i * 64 + lane];
#pragma unroll
    for (int e = 0; e < NEXP; ++e) acc[e] += xv * gw[e * HDIM + i * 64 + lane];
  }
#pragma unroll
  for (int e = 0; e < NEXP; ++e) {
#pragma unroll
    for (int off = 32; off >= 1; off >>= 1) acc[e] += __shfl_xor(acc[e], off);
  }
  if (lane == 0) {
    float m = acc[0];
#pragma unroll
    for (int e = 1; e < NEXP; ++e) m = fmaxf(m, acc[e]);
    float p[NEXP], Z = 0.f;
#pragma unroll
    for (int e = 0; e < NEXP; ++e) { p[e] = expf(acc[e] - m); Z += p[e]; }
    // top-2, jax.lax.top_k tie semantics (lower index wins)
    int i0 = 0; float b0 = p[0];
#pragma unroll
    for (int e = 1; e < NEXP; ++e) if (p[e] > b0) { b0 = p[e]; i0 = e; }
    int i1 = -1; float b1v = -1.f;
#pragma unroll
    for (int e = 0; e < NEXP; ++e) if (e != i0 && p[e] > b1v) { b1v = p[e]; i1 = e; }
    float logz = m + logf(Z);
    float ew0 = p[i0] / Z, ew1 = p[i1] / Z;
    atomicAdd(scal + 0, logz * logz);
    atomicAdd(scal + 1, (i0 == 0 || i1 == 0) ? 1.f : 0.f);
    atomicAdd(scal + 2, (i0 == 1 || i1 == 1) ? 1.f : 0.f);
    atomicAdd(scal + 3, ew0);
    atomicAdd(scal + 4, ew1);
    float s = ew0 + ew1;
    aw[t * 2]     = ew0 / s;
    aw[t * 2 + 1] = ew1 / s;
    int pos0 = atomicAdd(counts + i0, 1);
    lists[i0 * NASSIGN + pos0] = t * 2;
    int pos1 = atomicAdd(counts + i1, 1);
    lists[i1 * NASSIGN + pos1] = t * 2 + 1;
  }
}

__global__ void finalize_losses(const float* __restrict__ scal, float* __restrict__ tail) {
  if (threadIdx.x == 0 && blockIdx.x == 0) {
    const float invT = 1.f / (float)T_TOK;
    tail[0] = scal[0] * invT;  // z_loss
    float t0 = scal[1] * invT, t1 = scal[2] * invT;
    float r0 = scal[3] * invT, r1 = scal[4] * invT;
    tail[1] = 2.f * (t0 * r0 + t1 * r1);  // aux: mean(tpe*rpe)*k^2, k=2
  }
}

// ---------- grouped GEMM, m97 structure: 128x128 tile, BK=32, 4 waves ----------
// EPI==0: A = x_bf16 gathered (row = a>>1), out h1[a][f] = silu(acc + b1) as bf16. K=1024,N=4096
// EPI==1: A = h1 gathered (row = a),      atomicAdd(final[t][h], aw*(acc + b2)). K=4096,N=1024
template <int EPI>
__global__ __launch_bounds__(256) void moe_gemm(const u16* __restrict__ A,
                                                const u16* __restrict__ Bt,
                                                const float* __restrict__ bias,
                                                const int* __restrict__ counts,
                                                const int* __restrict__ lists,
                                                const float* __restrict__ aw,
                                                u16* __restrict__ h1out,
                                                float* __restrict__ fout,
                                                int K, int N) {
  int e = blockIdx.z;
  int Ne = counts[e];
  int m0 = blockIdx.y * 128;
  if (m0 >= Ne) return;
  int n0 = blockIdx.x * 128;

  __shared__ u16 lA[128 * 32];
  __shared__ u16 lB[128 * 32];
  __shared__ int l_list[128];
  __shared__ float l_aw[128];

  int tid = threadIdx.x;
  if (tid < 128) {
    int i = m0 + tid;
    int a = lists[e * NASSIGN + (i < Ne ? i : 0)];  // clamp: duplicate row 0 (writes guarded)
    l_list[tid] = a;
    l_aw[tid] = aw[a];
  }
  __syncthreads();

  // staging addresses: linear LDS, dest = wave_base + lane*16B; per-lane global src
  int rA0 = tid >> 2;                 // 0..63
  int koff = (tid & 3) * 8;           // bf16 elems within the 32-elem K chunk
  int a0 = l_list[rA0], a1 = l_list[rA0 + 64];
  size_t rowid0 = (EPI == 0) ? (size_t)(a0 >> 1) : (size_t)a0;
  size_t rowid1 = (EPI == 0) ? (size_t)(a1 >> 1) : (size_t)a1;
  const u16* srcA0 = A + rowid0 * K + koff;
  const u16* srcA1 = A + rowid1 * K + koff;
  const u16* srcB0 = Bt + ((size_t)e * N + n0 + rA0) * K + koff;
  const u16* srcB1 = srcB0 + (size_t)64 * K;

  int wv = tid >> 6, lane = tid & 63;
  int wr = wv >> 1, wc = wv & 1;
  u16* dA0 = lA + wv * 512;           // bytes: wv*1024
  u16* dA1 = lA + 2048 + wv * 512;
  u16* dB0 = lB + wv * 512;
  u16* dB1 = lB + 2048 + wv * 512;

  f32x4 acc[4][4] = {};
  int lr = lane & 15, lk = lane >> 4;

  int nk = K >> 5;
  for (int kt = 0; kt < nk; ++kt) {
    int kb = kt * 32;
    gload16(srcA0 + kb, dA0);
    gload16(srcA1 + kb, dA1);
    gload16(srcB0 + kb, dB0);
    gload16(srcB1 + kb, dB1);
    __syncthreads();
    short8 af[4], bf[4];
#pragma unroll
    for (int m = 0; m < 4; ++m)
      af[m] = *(const short8*)&lA[(wr * 64 + m * 16 + lr) * 32 + lk * 8];
#pragma unroll
    for (int n = 0; n < 4; ++n)
      bf[n] = *(const short8*)&lB[(wc * 64 + n * 16 + lr) * 32 + lk * 8];
#pragma unroll
    for (int m = 0; m < 4; ++m)
#pragma unroll
      for (int n = 0; n < 4; ++n)
        acc[m][n] = __builtin_amdgcn_mfma_f32_16x16x32_bf16(af[m], bf[n], acc[m][n], 0, 0, 0);
    __syncthreads();
  }

  // epilogue: C/D layout col=lane&15, row=(lane>>4)*4+r
#pragma unroll
  for (int m = 0; m < 4; ++m) {
#pragma unroll
    for (int r = 0; r < 4; ++r) {
      int rowLocal = wr * 64 + m * 16 + lk * 4 + r;
      int gi = m0 + rowLocal;
      if (gi >= Ne) continue;
      int a = l_list[rowLocal];
#pragma unroll
      for (int n = 0; n < 4; ++n) {
        int colLocal = wc * 64 + n * 16 + lr;
        int gc = n0 + colLocal;
        float v = acc[m][n][r] + bias[e * N + gc];
        if (EPI == 0) {
          v = v / (1.f + __expf(-v));            // silu
          h1out[(size_t)a * N + gc] = f2bf(v);
        } else {
          int t = a >> 1;
          atomicAdd(&fout[(size_t)t * N + gc], l_aw[rowLocal] * v);
        }
      }
    }
  }
}

extern "C" void kernel_launch(void* const* d_in, const int* in_sizes, int n_in,
                              void* d_out, int out_size, void* d_ws, size_t ws_size,
                              hipStream_t stream) {
  const float* x  = (const float*)d_in[0];
  const float* gw = (const float*)d_in[1];
  const float* w1 = (const float*)d_in[2];
  const float* b1 = (const float*)d_in[3];
  const float* w2 = (const float*)d_in[4];
  const float* b2 = (const float*)d_in[5];
  float* out = (float*)d_out;

  if (ws_size < WS_END) {
    fprintf(stderr, "kernel_launch: ws_size %zu < needed %zu\n", ws_size, WS_END);
    return;
  }

  char* ws = (char*)d_ws;
  float* scal  = (float*)(ws + WS_SCAL);
  int* counts  = (int*)(ws + WS_CNT);
  int* lists   = (int*)(ws + WS_LIST);
  float* aw    = (float*)(ws + WS_AW);
  u16* xb      = (u16*)(ws + WS_XBF);
  u16* w1t     = (u16*)(ws + WS_W1T);
  u16* w2t     = (u16*)(ws + WS_W2T);
  u16* h1      = (u16*)(ws + WS_H1);

  hipMemsetAsync(d_out, 0, (size_t)out_size * sizeof(float), stream);
  hipMemsetAsync(d_ws, 0, 256, stream);

  cvt_x_kernel<<<(T_TOK * HDIM) / (256 * 4), 256, 0, stream>>>(x, xb);
  router_kernel<<<T_TOK / 4, 256, 0, stream>>>(x, gw, scal, counts, lists, aw);
  // w1 [E][H][F] -> w1t [E][F][H]
  transpose_cvt<<<dim3(FDIM / 64, HDIM / 64, NEXP), 256, 0, stream>>>(w1, w1t, HDIM, FDIM);
  // w2 [E][F][H] -> w2t [E][H][F]
  transpose_cvt<<<dim3(HDIM / 64, FDIM / 64, NEXP), 256, 0, stream>>>(w2, w2t, FDIM, HDIM);
  finalize_losses<<<1, 64, 0, stream>>>(scal, out + (size_t)T_TOK * HDIM);

  // GEMM1: h1 = silu(x @ w1 + b1), grouped by expert. worst-case 64 M-tiles/expert
  moe_gemm<0><<<dim3(FDIM / 128, NASSIGN / 128, NEXP), 256, 0, stream>>>(
      xb, w1t, b1, counts, lists, aw, h1, nullptr, HDIM, FDIM);
  // GEMM2: final += aw * (h1 @ w2 + b2)
  moe_gemm<1><<<dim3(HDIM / 128, NASSIGN / 128, NEXP), 256, 0, stream>>>(
      h1, w2t, b2, counts, lists, aw, nullptr, out, FDIM, HDIM);
}

// Round 3
// 652.613 us; speedup vs baseline: 1.4177x; 1.4177x over previous
//
#include <hip/hip_runtime.h>
#include <hip/hip_bf16.h>
#include <cstdint>
#include <cstdio>

// DroplessMoE on MI355X.
// Sizes (fixed by setup_inputs): B=4,S=1024 -> T=4096 tokens, H=1024, F=4096, E=8, top-2.
// d_in: x[T,H] f32, gate_w[E,H] f32, w1[E,H,F] f32, b1[E,F] f32, w2[E,F,H] f32, b2[E,H] f32
// d_out: final[T,H] f32, then z_loss, aux_loss (out_size = T*H + 2)

typedef uint16_t u16;
typedef __attribute__((ext_vector_type(8))) short short8;
typedef __attribute__((ext_vector_type(4))) float f32x4;

#define T_TOK 4096
#define HDIM  1024
#define FDIM  4096
#define NEXP  8
#define NASSIGN (T_TOK * 2)   // total (token,slot) assignments = 8192 exactly

// ---------- ws layout (bytes) ----------
static constexpr size_t WS_PART = 0;                                       // 1024 blocks * 8 floats
static constexpr size_t WS_TOK  = WS_PART + 1024 * 8 * 4;                  // T ints (packed top-2)
static constexpr size_t WS_CNT  = WS_TOK + (size_t)T_TOK * 4;              // 8 ints
static constexpr size_t WS_LIST = WS_CNT + 256;                            // 8 * 8192 ints
static constexpr size_t WS_AW   = WS_LIST + (size_t)NEXP * NASSIGN * 4;    // 8192 floats
static constexpr size_t WS_XBF  = WS_AW + (size_t)NASSIGN * 4;             // T*H bf16
static constexpr size_t WS_W1T  = WS_XBF + (size_t)T_TOK * HDIM * 2;       // E*F*H bf16 (transposed)
static constexpr size_t WS_W2T  = WS_W1T + (size_t)NEXP * FDIM * HDIM * 2; // E*H*F bf16 (transposed)
static constexpr size_t WS_H1   = WS_W2T + (size_t)NEXP * FDIM * HDIM * 2; // NASSIGN*F bf16
static constexpr size_t WS_END  = WS_H1 + (size_t)NASSIGN * FDIM * 2;      // ~210 MB

__device__ __forceinline__ u16 f2bf(float v) {
  union { float f; uint32_t u; } c; c.f = v;
  uint32_t r = c.u + 0x7fffu + ((c.u >> 16) & 1u);
  return (u16)(r >> 16);
}

__device__ __forceinline__ void gload16(const void* g, void* l) {
  __builtin_amdgcn_global_load_lds(
      (const __attribute__((address_space(1))) void*)g,
      (__attribute__((address_space(3))) void*)l, 16, 0, 0);
}

// ---------- x fp32 -> bf16 ----------
__global__ __launch_bounds__(256) void cvt_x_kernel(const float* __restrict__ x,
                                                    u16* __restrict__ xb) {
  int i = blockIdx.x * 256 + threadIdx.x;       // grid covers T*H/4
  float4 v = ((const float4*)x)[i];
  ushort4 o;
  o.x = f2bf(v.x); o.y = f2bf(v.y); o.z = f2bf(v.z); o.w = f2bf(v.w);
  ((ushort4*)xb)[i] = o;
}

// ---------- tiled transpose + fp32->bf16:  src [E][R][C] f32 -> dst [E][C][R] bf16 ----------
__global__ __launch_bounds__(256) void transpose_cvt(const float* __restrict__ src,
                                                     u16* __restrict__ dst,
                                                     int R, int C) {
  int e = blockIdx.z;
  const float* s = src + (size_t)e * R * C;
  u16* d = dst + (size_t)e * R * C;
  int r0 = blockIdx.y * 64, c0 = blockIdx.x * 64;
  __shared__ u16 tile[64][68];                     // +4 u16 pad keeps 8B align, ~2-way banks
  int tid = threadIdx.x;
  int c4 = (tid & 15) * 4, rr = tid >> 4;
#pragma unroll
  for (int i = 0; i < 4; ++i) {
    int r = i * 16 + rr;
    float4 v = *(const float4*)&s[(size_t)(r0 + r) * C + c0 + c4];
    ushort4 o;
    o.x = f2bf(v.x); o.y = f2bf(v.y); o.z = f2bf(v.z); o.w = f2bf(v.w);
    *(ushort4*)&tile[r][c4] = o;
  }
  __syncthreads();
  int p = tid & 31, orr = tid >> 5;
#pragma unroll
  for (int i = 0; i < 8; ++i) {
    int orow = i * 8 + orr;                         // out row within tile (C dim)
    uint32_t pk = (uint32_t)tile[2 * p][orow] | ((uint32_t)tile[2 * p + 1][orow] << 16);
    *(uint32_t*)&d[(size_t)(c0 + orow) * R + r0 + 2 * p] = pk;
  }
}

// ---------- router: logits, softmax, top-2; NO global atomics ----------
// part[b][0..4] = block-partial {sum logz^2, mask0, mask1, sum ew0, sum ew1}
// tokinfo[t] = i0 | (i1<<4);  aw[t*2+s] = normalized weight
__global__ __launch_bounds__(256) void router_kernel(const float* __restrict__ x,
                                                     const float* __restrict__ gw,
                                                     float* __restrict__ part,
                                                     int* __restrict__ tokinfo,
                                                     float* __restrict__ aw) {
  int wv = threadIdx.x >> 6, lane = threadIdx.x & 63;
  int t = blockIdx.x * 4 + wv;
  const float* xr = x + (size_t)t * HDIM;
  float acc[NEXP] = {0.f, 0.f, 0.f, 0.f, 0.f, 0.f, 0.f, 0.f};
#pragma unroll
  for (int i = 0; i < 16; ++i) {
    float xv = xr[i * 64 + lane];
#pragma unroll
    for (int e = 0; e < NEXP; ++e) acc[e] += xv * gw[e * HDIM + i * 64 + lane];
  }
#pragma unroll
  for (int e = 0; e < NEXP; ++e) {
#pragma unroll
    for (int off = 32; off >= 1; off >>= 1) acc[e] += __shfl_xor(acc[e], off);
  }
  __shared__ float s_part[4][8];
  if (lane == 0) {
    float m = acc[0];
#pragma unroll
    for (int e = 1; e < NEXP; ++e) m = fmaxf(m, acc[e]);
    float p[NEXP], Z = 0.f;
#pragma unroll
    for (int e = 0; e < NEXP; ++e) { p[e] = expf(acc[e] - m); Z += p[e]; }
    // top-2, jax.lax.top_k tie semantics (lower index wins)
    int i0 = 0; float b0 = p[0];
#pragma unroll
    for (int e = 1; e < NEXP; ++e) if (p[e] > b0) { b0 = p[e]; i0 = e; }
    int i1 = -1; float b1v = -1.f;
#pragma unroll
    for (int e = 0; e < NEXP; ++e) if (e != i0 && p[e] > b1v) { b1v = p[e]; i1 = e; }
    float logz = m + logf(Z);
    float ew0 = p[i0] / Z, ew1 = p[i1] / Z;
    float s = ew0 + ew1;
    aw[t * 2]     = ew0 / s;
    aw[t * 2 + 1] = ew1 / s;
    tokinfo[t] = i0 | (i1 << 4);
    s_part[wv][0] = logz * logz;
    s_part[wv][1] = (i0 == 0 || i1 == 0) ? 1.f : 0.f;
    s_part[wv][2] = (i0 == 1 || i1 == 1) ? 1.f : 0.f;
    s_part[wv][3] = ew0;
    s_part[wv][4] = ew1;
  }
  __syncthreads();
  if (threadIdx.x < 5) {
    int i = threadIdx.x;
    part[blockIdx.x * 8 + i] =
        s_part[0][i] + s_part[1][i] + s_part[2][i] + s_part[3][i];
  }
}

// ---------- build per-expert lists from tokinfo; single block, LDS atomics ----------
__global__ __launch_bounds__(1024) void scatter_kernel(const int* __restrict__ tokinfo,
                                                       int* __restrict__ counts,
                                                       int* __restrict__ lists) {
  __shared__ int cur[NEXP];
  int tid = threadIdx.x;
  if (tid < NEXP) cur[tid] = 0;
  __syncthreads();
#pragma unroll
  for (int j = 0; j < 4; ++j) {
    int t = tid * 4 + j;
    int info = tokinfo[t];
    int e0 = info & 15, e1 = info >> 4;
    int pos0 = atomicAdd(&cur[e0], 1);
    lists[e0 * NASSIGN + pos0] = t * 2;
    int pos1 = atomicAdd(&cur[e1], 1);
    lists[e1 * NASSIGN + pos1] = t * 2 + 1;
  }
  __syncthreads();
  if (tid < NEXP) counts[tid] = cur[tid];
}

__global__ __launch_bounds__(512) void finalize_losses(const float* __restrict__ part,
                                                       float* __restrict__ tail) {
  int wv = threadIdx.x >> 6, lane = threadIdx.x & 63;
  __shared__ float s[8];
  if (wv < 5) {
    float v = 0.f;
#pragma unroll
    for (int k = 0; k < 16; ++k) v += part[(size_t)(lane + k * 64) * 8 + wv];
#pragma unroll
    for (int off = 32; off >= 1; off >>= 1) v += __shfl_xor(v, off);
    if (lane == 0) s[wv] = v;
  }
  __syncthreads();
  if (threadIdx.x == 0) {
    const float invT = 1.f / (float)T_TOK;
    tail[0] = s[0] * invT;                                  // z_loss
    float t0 = s[1] * invT, t1 = s[2] * invT;
    float r0 = s[3] * invT, r1 = s[4] * invT;
    tail[1] = 2.f * (t0 * r0 + t1 * r1);                    // aux, k=2
  }
}

// ---------- grouped GEMM, m97 structure: 128x128 tile, BK=32, 4 waves ----------
// EPI==0: A = x_bf16 gathered (row = a>>1), out h1[a][f] = silu(acc + b1) as bf16. K=1024,N=4096
// EPI==1: A = h1 gathered (row = a),      atomicAdd(final[t][h], aw*(acc + b2)). K=4096,N=1024
template <int EPI>
__global__ __launch_bounds__(256) void moe_gemm(const u16* __restrict__ A,
                                                const u16* __restrict__ Bt,
                                                const float* __restrict__ bias,
                                                const int* __restrict__ counts,
                                                const int* __restrict__ lists,
                                                const float* __restrict__ aw,
                                                u16* __restrict__ h1out,
                                                float* __restrict__ fout,
                                                int K, int N) {
  int e = blockIdx.z;
  int Ne = counts[e];
  int m0 = blockIdx.y * 128;
  if (m0 >= Ne) return;
  int n0 = blockIdx.x * 128;

  __shared__ u16 lA[128 * 32];
  __shared__ u16 lB[128 * 32];
  __shared__ int l_list[128];
  __shared__ float l_aw[128];

  int tid = threadIdx.x;
  if (tid < 128) {
    int i = m0 + tid;
    int a = lists[e * NASSIGN + (i < Ne ? i : 0)];  // clamp: duplicate row 0 (writes guarded)
    l_list[tid] = a;
    l_aw[tid] = aw[a];
  }
  __syncthreads();

  // staging addresses: linear LDS, dest = wave_base + lane*16B; per-lane global src
  int rA0 = tid >> 2;                 // 0..63
  int koff = (tid & 3) * 8;           // bf16 elems within the 32-elem K chunk
  int a0 = l_list[rA0], a1 = l_list[rA0 + 64];
  size_t rowid0 = (EPI == 0) ? (size_t)(a0 >> 1) : (size_t)a0;
  size_t rowid1 = (EPI == 0) ? (size_t)(a1 >> 1) : (size_t)a1;
  const u16* srcA0 = A + rowid0 * K + koff;
  const u16* srcA1 = A + rowid1 * K + koff;
  const u16* srcB0 = Bt + ((size_t)e * N + n0 + rA0) * K + koff;
  const u16* srcB1 = srcB0 + (size_t)64 * K;

  int wv = tid >> 6, lane = tid & 63;
  int wr = wv >> 1, wc = wv & 1;
  u16* dA0 = lA + wv * 512;           // bytes: wv*1024
  u16* dA1 = lA + 2048 + wv * 512;
  u16* dB0 = lB + wv * 512;
  u16* dB1 = lB + 2048 + wv * 512;

  f32x4 acc[4][4] = {};
  int lr = lane & 15, lk = lane >> 4;

  int nk = K >> 5;
  for (int kt = 0; kt < nk; ++kt) {
    int kb = kt * 32;
    gload16(srcA0 + kb, dA0);
    gload16(srcA1 + kb, dA1);
    gload16(srcB0 + kb, dB0);
    gload16(srcB1 + kb, dB1);
    __syncthreads();
    short8 af[4], bf[4];
#pragma unroll
    for (int m = 0; m < 4; ++m)
      af[m] = *(const short8*)&lA[(wr * 64 + m * 16 + lr) * 32 + lk * 8];
#pragma unroll
    for (int n = 0; n < 4; ++n)
      bf[n] = *(const short8*)&lB[(wc * 64 + n * 16 + lr) * 32 + lk * 8];
#pragma unroll
    for (int m = 0; m < 4; ++m)
#pragma unroll
      for (int n = 0; n < 4; ++n)
        acc[m][n] = __builtin_amdgcn_mfma_f32_16x16x32_bf16(af[m], bf[n], acc[m][n], 0, 0, 0);
    __syncthreads();
  }

  // epilogue: C/D layout col=lane&15, row=(lane>>4)*4+r
#pragma unroll
  for (int m = 0; m < 4; ++m) {
#pragma unroll
    for (int r = 0; r < 4; ++r) {
      int rowLocal = wr * 64 + m * 16 + lk * 4 + r;
      int gi = m0 + rowLocal;
      if (gi >= Ne) continue;
      int a = l_list[rowLocal];
#pragma unroll
      for (int n = 0; n < 4; ++n) {
        int colLocal = wc * 64 + n * 16 + lr;
        int gc = n0 + colLocal;
        float v = acc[m][n][r] + bias[e * N + gc];
        if (EPI == 0) {
          v = v / (1.f + __expf(-v));            // silu
          h1out[(size_t)a * N + gc] = f2bf(v);
        } else {
          int t = a >> 1;
          atomicAdd(&fout[(size_t)t * N + gc], l_aw[rowLocal] * v);
        }
      }
    }
  }
}

extern "C" void kernel_launch(void* const* d_in, const int* in_sizes, int n_in,
                              void* d_out, int out_size, void* d_ws, size_t ws_size,
                              hipStream_t stream) {
  const float* x  = (const float*)d_in[0];
  const float* gw = (const float*)d_in[1];
  const float* w1 = (const float*)d_in[2];
  const float* b1 = (const float*)d_in[3];
  const float* w2 = (const float*)d_in[4];
  const float* b2 = (const float*)d_in[5];
  float* out = (float*)d_out;

  if (ws_size < WS_END) {
    fprintf(stderr, "kernel_launch: ws_size %zu < needed %zu\n", ws_size, WS_END);
    return;
  }

  char* ws = (char*)d_ws;
  float* part  = (float*)(ws + WS_PART);
  int* tokinfo = (int*)(ws + WS_TOK);
  int* counts  = (int*)(ws + WS_CNT);
  int* lists   = (int*)(ws + WS_LIST);
  float* aw    = (float*)(ws + WS_AW);
  u16* xb      = (u16*)(ws + WS_XBF);
  u16* w1t     = (u16*)(ws + WS_W1T);
  u16* w2t     = (u16*)(ws + WS_W2T);
  u16* h1      = (u16*)(ws + WS_H1);

  hipMemsetAsync(d_out, 0, (size_t)out_size * sizeof(float), stream);

  cvt_x_kernel<<<(T_TOK * HDIM) / (256 * 4), 256, 0, stream>>>(x, xb);
  router_kernel<<<T_TOK / 4, 256, 0, stream>>>(x, gw, part, tokinfo, aw);
  scatter_kernel<<<1, 1024, 0, stream>>>(tokinfo, counts, lists);
  finalize_losses<<<1, 512, 0, stream>>>(part, out + (size_t)T_TOK * HDIM);
  // w1 [E][H][F] -> w1t [E][F][H]
  transpose_cvt<<<dim3(FDIM / 64, HDIM / 64, NEXP), 256, 0, stream>>>(w1, w1t, HDIM, FDIM);
  // w2 [E][F][H] -> w2t [E][H][F]
  transpose_cvt<<<dim3(HDIM / 64, FDIM / 64, NEXP), 256, 0, stream>>>(w2, w2t, FDIM, HDIM);

  // GEMM1: h1 = silu(x @ w1 + b1), grouped by expert. worst-case 64 M-tiles/expert
  moe_gemm<0><<<dim3(FDIM / 128, NASSIGN / 128, NEXP), 256, 0, stream>>>(
      xb, w1t, b1, counts, lists, aw, h1, nullptr, HDIM, FDIM);
  // GEMM2: final += aw * (h1 @ w2 + b2)
  moe_gemm<1><<<dim3(HDIM / 128, NASSIGN / 128, NEXP), 256, 0, stream>>>(
      h1, w2t, b2, counts, lists, aw, nullptr, out, FDIM, HDIM);
}